// Round 17
// baseline (989.399 us; speedup 1.0000x reference)
//
#include <hip/hip_runtime.h>
#include <hip/hip_bf16.h>

typedef __attribute__((ext_vector_type(8))) short bf16x8;
typedef __attribute__((ext_vector_type(4))) float f32x4;
typedef unsigned short u16;

__device__ __forceinline__ u16 f2b(float f) {
  __hip_bfloat16 h = __float2bfloat16(f);
  return __builtin_bit_cast(unsigned short, h);
}
__device__ __forceinline__ float b2f(u16 u) {
  __hip_bfloat16 h = __builtin_bit_cast(__hip_bfloat16, u);
  return __bfloat162float(h);
}

#define BAR() __builtin_amdgcn_s_barrier()
#define LGKM0() do { asm volatile("s_waitcnt lgkmcnt(0)" ::: "memory"); __builtin_amdgcn_sched_barrier(0); } while (0)
#define LGKM4() do { asm volatile("s_waitcnt lgkmcnt(4)" ::: "memory"); __builtin_amdgcn_sched_barrier(0); } while (0)
#define LGKM8() do { asm volatile("s_waitcnt lgkmcnt(8)" ::: "memory"); __builtin_amdgcn_sched_barrier(0); } while (0)
#define VMCNT4() asm volatile("s_waitcnt vmcnt(4)" ::: "memory")
#define VMCNT2() asm volatile("s_waitcnt vmcnt(2)" ::: "memory")
#define VMCNT0() asm volatile("s_waitcnt vmcnt(0)" ::: "memory")

#define EPI_HID 0
#define EPI_QK 1
#define EPI_PV 3
#define EPI_OUT 4

// ---------- 128^2 2-phase kernel (QK: N=128; OUT: N=512) ----------
__device__ __forceinline__ void stage_tile(char* sbase, const char* gbase, int ld_bytes, int tid) {
#pragma unroll
  for (int i = 0; i < 4; ++i) {
    int o = (i * 256 + tid) * 16;
    int row = o >> 7;
    int cb = o & 127;
    int scb = cb ^ ((row & 7) << 4);
    const char* src = gbase + (long)row * ld_bytes + scb;
    __builtin_amdgcn_global_load_lds((const __attribute__((address_space(1))) void*)src,
                                     (__attribute__((address_space(3))) void*)(sbase + o),
                                     16, 0, 0);
  }
}

template <int EPI>
__global__ __launch_bounds__(256, 2) void gemm_tn(
    const char* Ab, const char* Bb, long sAbat, long sBbat,
    int lda_b, int ldb_b, int nkt,
    u16* o0, u16* o1,
    const float* a0, const float* a1, const float* a2, const float* a3,
    float* fout, const float* xres) {
  __shared__ __align__(16) char lds[32768];
  char* sA = lds;
  char* sB = lds + 16384;
  const int tid = threadIdx.x;
  const int lane = tid & 63;
  const int wave = tid >> 6;
  const int wm = wave >> 1, wn = wave & 1;
  const int l16 = lane & 15, lq = lane >> 4;
  const int bat = blockIdx.z;
  const int row0 = blockIdx.y * 128;
  const int col0 = blockIdx.x * 128;

  const char* Abase = Ab + (long)bat * sAbat + (long)row0 * lda_b;
  const char* Bbase = Bb + (long)bat * sBbat + (long)col0 * ldb_b;

  f32x4 acc[4][4];
#pragma unroll
  for (int i = 0; i < 4; ++i)
#pragma unroll
    for (int j = 0; j < 4; ++j) acc[i][j] = (f32x4){0.f, 0.f, 0.f, 0.f};

  for (int kt = 0; kt < nkt; ++kt) {
    stage_tile(sA, Abase + (long)kt * 128, lda_b, tid);
    stage_tile(sB, Bbase + (long)kt * 128, ldb_b, tid);
    __syncthreads();
#pragma unroll
    for (int kk = 0; kk < 2; ++kk) {
      bf16x8 af[4], bfr[4];
#pragma unroll
      for (int mf = 0; mf < 4; ++mf) {
        int r = wm * 64 + mf * 16 + l16;
        int kb = kk * 64 + lq * 16;
        af[mf] = *(const bf16x8*)(sA + r * 128 + (kb ^ ((r & 7) << 4)));
      }
#pragma unroll
      for (int nf = 0; nf < 4; ++nf) {
        int r = wn * 64 + nf * 16 + l16;
        int kb = kk * 64 + lq * 16;
        bfr[nf] = *(const bf16x8*)(sB + r * 128 + (kb ^ ((r & 7) << 4)));
      }
#pragma unroll
      for (int mf = 0; mf < 4; ++mf)
#pragma unroll
        for (int nf = 0; nf < 4; ++nf)
          acc[mf][nf] = __builtin_amdgcn_mfma_f32_16x16x32_bf16(af[mf], bfr[nf], acc[mf][nf], 0, 0, 0);
    }
    __syncthreads();
  }

#pragma unroll
  for (int mf = 0; mf < 4; ++mf) {
#pragma unroll
    for (int nf = 0; nf < 4; ++nf) {
      const int row = row0 + wm * 64 + mf * 16 + lq * 4;
      const int col = col0 + wn * 64 + nf * 16 + l16;
      f32x4 v = acc[mf][nf];
      if constexpr (EPI == EPI_QK) {
        float qg = a0[col], qbt = a1[col], kg = a2[col], kbt = a3[col];
#pragma unroll
        for (int i = 0; i < 4; ++i) {
          float t = v[i];
          o0[(size_t)(row + i) * 128 + col] = f2b(t * qg + qbt);
          o1[(size_t)(row + i) * 128 + col] = f2b(t * kg + kbt);
        }
      } else if constexpr (EPI == EPI_OUT) {
        float bias = a0[col];
#pragma unroll
        for (int i = 0; i < 4; ++i)
          fout[(size_t)(row + i) * 512 + col] = v[i] + bias + xres[(size_t)(row + i) * 512 + col];
      }
    }
  }
}

// ---------- 256^2 16x16 minimal-barrier kernel (HID) — round-6 best ----------
__device__ __forceinline__ void stage_half(char* sbase, const char* gbase, long ld, int tid) {
#pragma unroll
  for (int i = 0; i < 2; ++i) {
    int o = (i * 512 + tid) * 16;
    int row = o >> 7;
    int cb = o & 127;
    int scb = cb ^ ((row & 7) << 4);
    const char* src = gbase + (long)row * ld + scb;
    __builtin_amdgcn_global_load_lds((const __attribute__((address_space(1))) void*)src,
                                     (__attribute__((address_space(3))) void*)(sbase + o),
                                     16, 0, 0);
  }
}

template <int EPI>
__global__ __launch_bounds__(512, 1) void gemm256(
    const char* Ab, const char* Bb, long sAbat, long sBbat,
    long lda, long ldb, int nkt, int nx,
    u16* o0, u16* o1,
    const float* a0, float* fout, const float* xres) {
  extern __shared__ __align__(16) char lds[];
  const int tid = threadIdx.x;
  const int lane = tid & 63;
  const int wave = tid >> 6;
  const int wm = wave >> 2;
  const int wn = wave & 3;
  const int l16 = lane & 15, lq = lane >> 4;
  const int bat = blockIdx.y;

  const int nwg = gridDim.x;
  const int qq = nwg >> 3;
  const int fid = blockIdx.x;
  const int swz = (fid & 7) * qq + (fid >> 3);
  const int row0 = (swz / nx) * 256;
  const int col0 = (swz % nx) * 256;

  const char* gA = Ab + (long)bat * sAbat + (long)row0 * lda;
  const char* gB = Bb + (long)bat * sBbat + (long)col0 * ldb;

  f32x4 acc[8][4];
#pragma unroll
  for (int i = 0; i < 8; ++i)
#pragma unroll
    for (int j = 0; j < 4; ++j) acc[i][j] = (f32x4){0.f, 0.f, 0.f, 0.f};

  const int kmask = (l16 & 7) << 4;
  const int kb0 = (lq * 16) ^ kmask;
  const int kb1 = (64 + lq * 16) ^ kmask;
  const int rB = (wn & 1) * 64;

  stage_half(lds + 32768, gB, ldb, tid);
  stage_half(lds + 32768 + 16384, gB + 128 * ldb, ldb, tid);
  stage_half(lds, gA, lda, tid);
  stage_half(lds + 16384, gA + 128 * lda, lda, tid);
  if (nkt > 1) {
    stage_half(lds + 65536 + 32768, gB + 128, ldb, tid);
    stage_half(lds + 65536 + 32768 + 16384, gB + 128 * ldb + 128, ldb, tid);
    VMCNT4();
  } else {
    VMCNT0();
  }
  BAR();

  bf16x8 af0[4], af1[4], afp0[4], afp1[4], bfr0[4], bfr1[4];
  {
    const char* myA = lds + wm * 16384;
    const char* myB = lds + 32768 + (wn >> 1) * 16384;
#pragma unroll
    for (int nf = 0; nf < 4; ++nf)
      bfr0[nf] = *(const bf16x8*)(myB + (rB + nf * 16 + l16) * 128 + kb0);
#pragma unroll
    for (int mf = 0; mf < 4; ++mf)
      af0[mf] = *(const bf16x8*)(myA + (mf * 16 + l16) * 128 + kb0);
  }

  for (int t = 0; t < nkt; ++t) {
    const char* bufc = lds + (t & 1) * 65536;
    const char* bufn = lds + ((t + 1) & 1) * 65536;
    const char* myA = bufc + wm * 16384;
    const char* myB = bufc + 32768 + (wn >> 1) * 16384;
    const char* nA = bufn + wm * 16384;
    const char* nB = bufn + 32768 + (wn >> 1) * 16384;
    char* stA = (char*)bufn;
    char* stB = (char*)bufc + 32768;
    const bool sA_ok = (t + 1) < nkt;
    const bool sB_ok = (t + 2) < nkt;

#pragma unroll
    for (int nf = 0; nf < 4; ++nf)
      bfr1[nf] = *(const bf16x8*)(myB + (rB + nf * 16 + l16) * 128 + kb1);
#pragma unroll
    for (int mf = 0; mf < 4; ++mf)
      af1[mf] = *(const bf16x8*)(myA + (mf * 16 + l16) * 128 + kb1);
    if (sA_ok) stage_half(stA, gA + (long)(t + 1) * 128, lda, tid);
    LGKM8();
    __builtin_amdgcn_s_setprio(1);
#pragma unroll
    for (int mf = 0; mf < 4; ++mf)
#pragma unroll
      for (int nf = 0; nf < 4; ++nf)
        acc[mf][nf] = __builtin_amdgcn_mfma_f32_16x16x32_bf16(af0[mf], bfr0[nf], acc[mf][nf], 0, 0, 0);
    __builtin_amdgcn_s_setprio(0);

#pragma unroll
    for (int mf = 0; mf < 4; ++mf)
      afp0[mf] = *(const bf16x8*)(myA + (64 + mf * 16 + l16) * 128 + kb0);
    if (sA_ok) stage_half(stA + 16384, gA + 128 * lda + (long)(t + 1) * 128, lda, tid);
    LGKM4();
    __builtin_amdgcn_s_setprio(1);
#pragma unroll
    for (int mf = 0; mf < 4; ++mf)
#pragma unroll
      for (int nf = 0; nf < 4; ++nf)
        acc[mf][nf] = __builtin_amdgcn_mfma_f32_16x16x32_bf16(af1[mf], bfr1[nf], acc[mf][nf], 0, 0, 0);
    __builtin_amdgcn_s_setprio(0);
    BAR();

#pragma unroll
    for (int mf = 0; mf < 4; ++mf)
      afp1[mf] = *(const bf16x8*)(myA + (64 + mf * 16 + l16) * 128 + kb1);
    if (sB_ok) stage_half(stB, gB + (long)(t + 2) * 128, ldb, tid);
    LGKM4();
    __builtin_amdgcn_s_setprio(1);
#pragma unroll
    for (int mf = 0; mf < 4; ++mf)
#pragma unroll
      for (int nf = 0; nf < 4; ++nf)
        acc[4 + mf][nf] = __builtin_amdgcn_mfma_f32_16x16x32_bf16(afp0[mf], bfr0[nf], acc[4 + mf][nf], 0, 0, 0);
    __builtin_amdgcn_s_setprio(0);
    if (sA_ok) {
      if (sB_ok) { VMCNT2(); } else { VMCNT0(); }
      BAR();
    }

    if (sA_ok) {
#pragma unroll
      for (int nf = 0; nf < 4; ++nf)
        bfr0[nf] = *(const bf16x8*)(nB + (rB + nf * 16 + l16) * 128 + kb0);
#pragma unroll
      for (int mf = 0; mf < 4; ++mf)
        af0[mf] = *(const bf16x8*)(nA + (mf * 16 + l16) * 128 + kb0);
    }
    if (sB_ok) stage_half(stB + 16384, gB + 128 * ldb + (long)(t + 2) * 128, ldb, tid);
    if (sA_ok) { LGKM8(); } else { LGKM0(); }
    __builtin_amdgcn_s_setprio(1);
#pragma unroll
    for (int mf = 0; mf < 4; ++mf)
#pragma unroll
      for (int nf = 0; nf < 4; ++nf)
        acc[4 + mf][nf] = __builtin_amdgcn_mfma_f32_16x16x32_bf16(afp1[mf], bfr1[nf], acc[4 + mf][nf], 0, 0, 0);
    __builtin_amdgcn_s_setprio(0);
    BAR();
  }

  // epilogue
#pragma unroll
  for (int mi = 0; mi < 8; ++mi) {
#pragma unroll
    for (int ni = 0; ni < 4; ++ni) {
      const int row = row0 + wm * 128 + mi * 16 + lq * 4;
      const int col = col0 + wn * 64 + ni * 16 + l16;
      f32x4 v = acc[mi][ni];
      if constexpr (EPI == EPI_HID) {
        float bias = a0[col];
        u16* dst = (col < 1024) ? (o0 + (size_t)col * 16384 + row)
                                : (o1 + (size_t)(col - 1024) * 16384 + row);
        *(ushort4*)dst = make_ushort4(f2b(v.x + bias), f2b(v.y + bias), f2b(v.z + bias), f2b(v.w + bias));
      }
    }
  }
}

// ---------- 1024-thread 256^2 PV kernel, 1 barrier/K-tile + dual-khalf prefetch ----------
// LDS 160KB: A 2x32K @0,32768; B ring 3x32K @65536+. 16 waves (4/SIMD).
// Both k-halves' 16 ds_reads issue together right after the barrier; P1 waits
// counted lgkmcnt(8) (kh0 only), so kh1's reads hide under P1's MFMA+stage.
__device__ __forceinline__ void stage1k(char* s, const char* g, long ld, int tid) {
  int o = tid * 16;
  int row = o >> 7;
  int scb = (o & 127) ^ ((row & 7) << 4);
  __builtin_amdgcn_global_load_lds((const __attribute__((address_space(1))) void*)(g + (long)row * ld + scb),
                                   (__attribute__((address_space(3))) void*)(s + o), 16, 0, 0);
}

__global__ __launch_bounds__(1024, 1) void gemm1k_pv(
    const char* Ab, const char* Bb, long sAbat, long sBbat,
    long lda, long ldb, int nkt,
    u16* o0, const u16* g_t) {
  extern __shared__ __align__(16) char lds[];
  const int tid = threadIdx.x;
  const int lane = tid & 63;
  const int wave = tid >> 6;          // 0..15
  const int wm = wave >> 2;           // 0..3 -> rows wm*64
  const int wn = wave & 3;            // 0..3 -> cols wn*64
  const int l16 = lane & 15, lq = lane >> 4;
  const int bat = blockIdx.y;

  const int fid = blockIdx.x;         // 64 per batch
  const int r = fid & 15;             // row-tile
  const int c = fid >> 4;             // col-tile
  const int row0 = r * 256;
  const int col0 = c * 256;

  const char* gA = Ab + (long)bat * sAbat + (long)row0 * lda;
  const char* gB = Bb + (long)bat * sBbat + (long)col0 * ldb;

  f32x4 acc[4][4];
#pragma unroll
  for (int i = 0; i < 4; ++i)
#pragma unroll
    for (int j = 0; j < 4; ++j) acc[i][j] = (f32x4){0.f, 0.f, 0.f, 0.f};

  const int kmask = (l16 & 7) << 4;
  const int kb0 = (lq * 16) ^ kmask;
  const int kb1 = (64 + lq * 16) ^ kmask;
  const int rA = (wm & 1) * 64;
  const int rB = (wn & 1) * 64;

  // prologue: B(0) @slot0, A(0) @buf0, B(1) @slot1; VMCNT2 leaves B(1) pending.
  stage1k(lds + 65536, gB, ldb, tid);
  stage1k(lds + 65536 + 16384, gB + 128 * ldb, ldb, tid);
  stage1k(lds, gA, lda, tid);
  stage1k(lds + 16384, gA + 128 * lda, lda, tid);
  if (nkt > 1) {
    stage1k(lds + 98304, gB + 128, ldb, tid);
    stage1k(lds + 98304 + 16384, gB + 128 * ldb + 128, ldb, tid);
    VMCNT2();
  } else {
    VMCNT0();
  }
  BAR();

  bf16x8 a0[4], b0[4], a1[4], b1[4];
  {
    const char* myA = lds + (wm >> 1) * 16384;
    const char* myB = lds + 65536 + (wn >> 1) * 16384;
#pragma unroll
    for (int mi = 0; mi < 4; ++mi)
      a0[mi] = *(const bf16x8*)(myA + (rA + mi * 16 + l16) * 128 + kb0);
#pragma unroll
    for (int ni = 0; ni < 4; ++ni)
      b0[ni] = *(const bf16x8*)(myB + (rB + ni * 16 + l16) * 128 + kb0);
#pragma unroll
    for (int mi = 0; mi < 4; ++mi)
      a1[mi] = *(const bf16x8*)(myA + (rA + mi * 16 + l16) * 128 + kb1);
#pragma unroll
    for (int ni = 0; ni < 4; ++ni)
      b1[ni] = *(const bf16x8*)(myB + (rB + ni * 16 + l16) * 128 + kb1);
  }

  int bs_c = 0;  // B ring slot of tile t (0..2)
  for (int t = 0; t < nkt; ++t) {
    const bool sA = (t + 1) < nkt;
    const bool sB = (t + 2) < nkt;
    const int bs_n = (bs_c + 1 == 3) ? 0 : bs_c + 1;  // slot of t+1
    const int bs_s = (bs_n + 1 == 3) ? 0 : bs_n + 1;  // slot of t+2 (stage target)

    // ---- P1: stage A(t+1); wait kh0 (counted, 8); MFMA kh0 (kh1 reads still flying)
    if (sA) {
      char* stA = lds + ((t + 1) & 1) * 32768;
      stage1k(stA, gA + (long)(t + 1) * 128, lda, tid);
      stage1k(stA + 16384, gA + 128 * lda + (long)(t + 1) * 128, lda, tid);
    }
    LGKM8();
    __builtin_amdgcn_s_setprio(1);
#pragma unroll
    for (int mi = 0; mi < 4; ++mi)
#pragma unroll
      for (int ni = 0; ni < 4; ++ni)
        acc[mi][ni] = __builtin_amdgcn_mfma_f32_16x16x32_bf16(a0[mi], b0[ni], acc[mi][ni], 0, 0, 0);
    __builtin_amdgcn_s_setprio(0);

    // ---- P2: stage B(t+2); wait kh1; MFMA kh1; VMCNT2+BAR; issue next tile's 16 reads
    if (sB) {
      char* stB = lds + 65536 + bs_s * 32768;
      stage1k(stB, gB + (long)(t + 2) * 128, ldb, tid);
      stage1k(stB + 16384, gB + 128 * ldb + (long)(t + 2) * 128, ldb, tid);
    }
    LGKM0();
    __builtin_amdgcn_s_setprio(1);
#pragma unroll
    for (int mi = 0; mi < 4; ++mi)
#pragma unroll
      for (int ni = 0; ni < 4; ++ni)
        acc[mi][ni] = __builtin_amdgcn_mfma_f32_16x16x32_bf16(a1[mi], b1[ni], acc[mi][ni], 0, 0, 0);
    __builtin_amdgcn_s_setprio(0);
    if (sA) {
      if (sB) { VMCNT2(); } else { VMCNT0(); }
      BAR();  // A(t+1), B(t+1) landed and visible
      const char* nA = lds + ((t + 1) & 1) * 32768 + (wm >> 1) * 16384;
      const char* nB = lds + 65536 + bs_n * 32768 + (wn >> 1) * 16384;
#pragma unroll
      for (int mi = 0; mi < 4; ++mi)
        a0[mi] = *(const bf16x8*)(nA + (rA + mi * 16 + l16) * 128 + kb0);
#pragma unroll
      for (int ni = 0; ni < 4; ++ni)
        b0[ni] = *(const bf16x8*)(nB + (rB + ni * 16 + l16) * 128 + kb0);
#pragma unroll
      for (int mi = 0; mi < 4; ++mi)
        a1[mi] = *(const bf16x8*)(nA + (rA + mi * 16 + l16) * 128 + kb1);
#pragma unroll
      for (int ni = 0; ni < 4; ++ni)
        b1[ni] = *(const bf16x8*)(nB + (rB + ni * 16 + l16) * 128 + kb1);
    }
    bs_c = bs_n;
  }

  // epilogue: * gate, store bf16 out1
#pragma unroll
  for (int mi = 0; mi < 4; ++mi) {
#pragma unroll
    for (int ni = 0; ni < 4; ++ni) {
      const int row = row0 + wm * 64 + mi * 16 + lq * 4;
      const int col = col0 + wn * 64 + ni * 16 + l16;
      f32x4 v = acc[mi][ni];
      const u16* gp = g_t + (size_t)col * 16384 + (size_t)bat * 4096 + row;
      ushort4 g = *(const ushort4*)gp;
      u16* dst = o0 + (size_t)bat * 4096 * 1024;
      dst[(size_t)(row + 0) * 1024 + col] = f2b(v.x * b2f(g.x));
      dst[(size_t)(row + 1) * 1024 + col] = f2b(v.y * b2f(g.y));
      dst[(size_t)(row + 2) * 1024 + col] = f2b(v.z * b2f(g.z));
      dst[(size_t)(row + 3) * 1024 + col] = f2b(v.w * b2f(g.w));
    }
  }
}

// ---------- lean single-stage ATTN (K=128 staged once), software-pipelined ----------
__device__ __forceinline__ void stage256(char* s, const char* g, int tid) {
#pragma unroll
  for (int i = 0; i < 8; ++i) {
    int o = (i * 512 + tid) * 16;
    int row = o >> 8;
    int cb = o & 255;
    int scb = cb ^ ((row & 7) << 4);
    __builtin_amdgcn_global_load_lds((const __attribute__((address_space(1))) void*)(g + (long)row * 256 + scb),
                                     (__attribute__((address_space(3))) void*)(s + o), 16, 0, 0);
  }
}

__global__ __launch_bounds__(512, 1) void attn_lean(
    const char* Kb, const char* Qb, u16* o0, int nx) {
  extern __shared__ __align__(16) char lds[];
  const int tid = threadIdx.x;
  const int lane = tid & 63;
  const int wave = tid >> 6;
  const int wm = wave >> 2;        // j half
  const int wn = wave & 3;         // q quarter
  const int l16 = lane & 15, lq = lane >> 4;
  const int bat = blockIdx.y;

  const int nwg = gridDim.x;       // 256 (%8==0)
  const int qq = nwg >> 3;
  const int fid = blockIdx.x;
  const int swz = (fid & 7) * qq + (fid >> 3);
  const int row0 = (swz / nx) * 256;   // j
  const int col0 = (swz % nx) * 256;   // q

  const char* gA = Kb + (size_t)bat * 4096 * 256 + (size_t)row0 * 256;
  const char* gB = Qb + (size_t)bat * 4096 * 256 + (size_t)col0 * 256;

  stage256(lds, gA, tid);
  stage256(lds + 65536, gB, tid);
  VMCNT0();
  BAR();

  const char* myA = lds + wm * 32768;                 // 128 j-rows x 256B
  const char* myB = lds + 65536 + (wn >> 1) * 32768;  // 128 q-rows x 256B
  const int rB = (wn & 1) * 64;
  const int kmask = (l16 & 7) << 4;

  f32x4 acc[8][4];
#pragma unroll
  for (int i = 0; i < 8; ++i)
#pragma unroll
    for (int j = 0; j < 4; ++j) acc[i][j] = (f32x4){0.f, 0.f, 0.f, 0.f};

  bf16x8 aC[8], bC[4], aN[8], bN[4];

#define LOADK(A, B, kk)                                                        \
  do {                                                                         \
    const int kb_ = ((kk) * 64 + lq * 16) ^ kmask;                             \
    _Pragma("unroll") for (int mf = 0; mf < 8; ++mf)                           \
        A[mf] = *(const bf16x8*)(myA + (mf * 16 + l16) * 256 + kb_);           \
    _Pragma("unroll") for (int nf = 0; nf < 4; ++nf)                           \
        B[nf] = *(const bf16x8*)(myB + (rB + nf * 16 + l16) * 256 + kb_);      \
  } while (0)
#define MMK(A, B)                                                              \
  do {                                                                         \
    _Pragma("unroll") for (int mf = 0; mf < 8; ++mf)                           \
        _Pragma("unroll") for (int nf = 0; nf < 4; ++nf)                       \
            acc[mf][nf] =                                                      \
        __builtin_amdgcn_mfma_f32_16x16x32_bf16(A[mf], B[nf], acc[mf][nf], 0, 0, 0); \
  } while (0)

  LOADK(aC, bC, 0);
  LOADK(aN, bN, 1);
  MMK(aC, bC);
  LOADK(aC, bC, 2);
  MMK(aN, bN);
  LOADK(aN, bN, 3);
  MMK(aC, bC);
  MMK(aN, bN);
#undef LOADK
#undef MMK

  const float scale = 0.088388347648318447f;  // 128^-0.5
  u16* dst = o0 + (size_t)bat * 4096 * 4096;
#pragma unroll
  for (int mi = 0; mi < 8; ++mi) {
#pragma unroll
    for (int ni = 0; ni < 4; ++ni) {
      const int row = row0 + wm * 128 + mi * 16 + lq * 4;   // j (4 consecutive)
      const int col = col0 + wn * 64 + ni * 16 + l16;       // q
      f32x4 v = acc[mi][ni];
      float t0 = v.x * scale; t0 = t0 > 0.f ? t0 * t0 : 0.f;
      float t1 = v.y * scale; t1 = t1 > 0.f ? t1 * t1 : 0.f;
      float t2 = v.z * scale; t2 = t2 > 0.f ? t2 * t2 : 0.f;
      float t3 = v.w * scale; t3 = t3 > 0.f ? t3 * t3 : 0.f;
      *(ushort4*)(dst + (size_t)col * 4096 + row) =
          make_ushort4(f2b(t0), f2b(t1), f2b(t2), f2b(t3));
    }
  }
}

__global__ void conv_b(const float* in, u16* out, int n) {
  int i = (blockIdx.x * blockDim.x + threadIdx.x) * 4;
  if (i >= n) return;
  float4 f = *(const float4*)(in + i);
  *(ushort4*)(out + i) = make_ushort4(f2b(f.x), f2b(f.y), f2b(f.z), f2b(f.w));
}

// out[c][r] = bf16(in[r][c]) via LDS 32x32 tile (+1 pad) — both sides coalesced
__global__ void transpose_lds(const float* in, u16* out, int R, int C) {
  __shared__ float t[32][33];
  const int tx = threadIdx.x & 31, ty = threadIdx.x >> 5;  // 32x8
  const int c0 = blockIdx.x * 32, r0 = blockIdx.y * 32;
#pragma unroll
  for (int i = 0; i < 32; i += 8)
    t[ty + i][tx] = in[(size_t)(r0 + ty + i) * C + c0 + tx];
  __syncthreads();
#pragma unroll
  for (int i = 0; i < 32; i += 8)
    out[(size_t)(c0 + ty + i) * R + r0 + tx] = f2b(t[tx][ty + i]);
}

extern "C" void kernel_launch(void* const* d_in, const int* in_sizes, int n_in,
                              void* d_out, int out_size, void* d_ws, size_t ws_size,
                              hipStream_t stream) {
  const float* x = (const float*)d_in[0];
  const float* w_hidden = (const float*)d_in[1];
  const float* b_hidden = (const float*)d_in[2];
  const float* w_qk = (const float*)d_in[3];
  const float* q_gamma = (const float*)d_in[4];
  const float* q_beta = (const float*)d_in[5];
  const float* k_gamma = (const float*)d_in[6];
  const float* k_beta = (const float*)d_in[7];
  const float* w_out = (const float*)d_in[8];
  const float* b_out = (const float*)d_in[9];
  float* out = (float*)d_out;

  char* ws = (char*)d_ws;
  size_t off = 0;
  auto alloc = [&](size_t bytes) { char* p = ws + off; off += (bytes + 255) & ~255ull; return p; };
  u16* xb     = (u16*)alloc(16384ull * 512 * 2);
  u16* wh_t   = (u16*)alloc(2048ull * 512 * 2);
  u16* wqk_t  = (u16*)alloc(128ull * 512 * 2);
  u16* wout_t = (u16*)alloc(512ull * 1024 * 2);
  u16* v_t    = (u16*)alloc(1024ull * 16384 * 2);
  u16* g_t    = (u16*)alloc(1024ull * 16384 * 2);
  u16* qb_a   = (u16*)alloc(16384ull * 128 * 2);
  u16* kb_a   = (u16*)alloc(16384ull * 128 * 2);
  u16* attnb  = (u16*)alloc(4ull * 4096 * 4096 * 2);
  u16* out1b  = (u16*)alloc(16384ull * 1024 * 2);

  (void)hipFuncSetAttribute((const void*)gemm256<EPI_HID>, hipFuncAttributeMaxDynamicSharedMemorySize, 131072);
  (void)hipFuncSetAttribute((const void*)gemm1k_pv, hipFuncAttributeMaxDynamicSharedMemorySize, 163840);
  (void)hipFuncSetAttribute((const void*)attn_lean, hipFuncAttributeMaxDynamicSharedMemorySize, 131072);

  conv_b<<<(16384 * 512 / 4 + 255) / 256, 256, 0, stream>>>(x, xb, 16384 * 512);
  transpose_lds<<<dim3(2048 / 32, 512 / 32), 256, 0, stream>>>(w_hidden, wh_t, 512, 2048);
  transpose_lds<<<dim3(128 / 32, 512 / 32), 256, 0, stream>>>(w_qk, wqk_t, 512, 128);
  transpose_lds<<<dim3(512 / 32, 1024 / 32), 256, 0, stream>>>(w_out, wout_t, 1024, 512);

  // GEMM1: hid = x @ Wh (+bias) -> v_t, g_t (transposed bf16). M=16384 N=2048 K=512
  gemm256<EPI_HID><<<dim3(512, 1), 512, 131072, stream>>>(
      (const char*)xb, (const char*)wh_t, 0, 0, 1024, 1024, 8, 8,
      v_t, g_t, b_hidden, nullptr, nullptr);
  // GEMM2: qk = x @ Wqk -> q,k (offset-scale). N=128
  gemm_tn<EPI_QK><<<dim3(1, 128, 1), 256, 0, stream>>>(
      (const char*)xb, (const char*)wqk_t, 0, 0, 1024, 1024, 8,
      qb_a, kb_a, q_gamma, q_beta, k_gamma, k_beta, nullptr, nullptr);
  // sim: C[j][q] = K @ Q^T, relu^2(scale*) -> attn[q][j] bf16 (lean single-stage)
  attn_lean<<<dim3(256, 4), 512, 131072, stream>>>(
      (const char*)kb_a, (const char*)qb_a, attnb, 16);
  // out1 = (attn @ v) * gate. per batch M=4096 N=1024 K=4096 — ring + dual-khalf prefetch
  gemm1k_pv<<<dim3(64, 4), 1024, 163840, stream>>>(
      (const char*)attnb, (const char*)v_t, 4096ll * 8192, 8192, 8192, 32768, 64,
      out1b, g_t);
  // out = out1 @ Wout + b_out + x. M=16384 N=512 K=1024
  gemm_tn<EPI_OUT><<<dim3(4, 128, 1), 256, 0, stream>>>(
      (const char*)out1b, (const char*)wout_t, 0, 0, 2048, 2048, 16,
      nullptr, nullptr, b_out, nullptr, nullptr, nullptr, out, x);
}

// Round 18
// 317.016 us; speedup vs baseline: 3.1210x; 3.1210x over previous
//
#include <hip/hip_runtime.h>
#include <hip/hip_bf16.h>

typedef __attribute__((ext_vector_type(8))) short bf16x8;
typedef __attribute__((ext_vector_type(4))) float f32x4;
typedef unsigned short u16;

__device__ __forceinline__ u16 f2b(float f) {
  __hip_bfloat16 h = __float2bfloat16(f);
  return __builtin_bit_cast(unsigned short, h);
}
__device__ __forceinline__ float b2f(u16 u) {
  __hip_bfloat16 h = __builtin_bit_cast(__hip_bfloat16, u);
  return __bfloat162float(h);
}

#define BAR() __builtin_amdgcn_s_barrier()
#define LGKM0() do { asm volatile("s_waitcnt lgkmcnt(0)" ::: "memory"); __builtin_amdgcn_sched_barrier(0); } while (0)
#define LGKM4() do { asm volatile("s_waitcnt lgkmcnt(4)" ::: "memory"); __builtin_amdgcn_sched_barrier(0); } while (0)
#define LGKM8() do { asm volatile("s_waitcnt lgkmcnt(8)" ::: "memory"); __builtin_amdgcn_sched_barrier(0); } while (0)
#define VMCNT4() asm volatile("s_waitcnt vmcnt(4)" ::: "memory")
#define VMCNT2() asm volatile("s_waitcnt vmcnt(2)" ::: "memory")
#define VMCNT0() asm volatile("s_waitcnt vmcnt(0)" ::: "memory")

#define EPI_HID 0
#define EPI_QK 1
#define EPI_PV 3
#define EPI_OUT 4

// ---------- 128^2 2-phase kernel (QK: N=128; OUT: N=512) ----------
__device__ __forceinline__ void stage_tile(char* sbase, const char* gbase, int ld_bytes, int tid) {
#pragma unroll
  for (int i = 0; i < 4; ++i) {
    int o = (i * 256 + tid) * 16;
    int row = o >> 7;
    int cb = o & 127;
    int scb = cb ^ ((row & 7) << 4);
    const char* src = gbase + (long)row * ld_bytes + scb;
    __builtin_amdgcn_global_load_lds((const __attribute__((address_space(1))) void*)src,
                                     (__attribute__((address_space(3))) void*)(sbase + o),
                                     16, 0, 0);
  }
}

template <int EPI>
__global__ __launch_bounds__(256, 2) void gemm_tn(
    const char* Ab, const char* Bb, long sAbat, long sBbat,
    int lda_b, int ldb_b, int nkt,
    u16* o0, u16* o1,
    const float* a0, const float* a1, const float* a2, const float* a3,
    float* fout, const float* xres) {
  __shared__ __align__(16) char lds[32768];
  char* sA = lds;
  char* sB = lds + 16384;
  const int tid = threadIdx.x;
  const int lane = tid & 63;
  const int wave = tid >> 6;
  const int wm = wave >> 1, wn = wave & 1;
  const int l16 = lane & 15, lq = lane >> 4;
  const int bat = blockIdx.z;
  const int row0 = blockIdx.y * 128;
  const int col0 = blockIdx.x * 128;

  const char* Abase = Ab + (long)bat * sAbat + (long)row0 * lda_b;
  const char* Bbase = Bb + (long)bat * sBbat + (long)col0 * ldb_b;

  f32x4 acc[4][4];
#pragma unroll
  for (int i = 0; i < 4; ++i)
#pragma unroll
    for (int j = 0; j < 4; ++j) acc[i][j] = (f32x4){0.f, 0.f, 0.f, 0.f};

  for (int kt = 0; kt < nkt; ++kt) {
    stage_tile(sA, Abase + (long)kt * 128, lda_b, tid);
    stage_tile(sB, Bbase + (long)kt * 128, ldb_b, tid);
    __syncthreads();
#pragma unroll
    for (int kk = 0; kk < 2; ++kk) {
      bf16x8 af[4], bfr[4];
#pragma unroll
      for (int mf = 0; mf < 4; ++mf) {
        int r = wm * 64 + mf * 16 + l16;
        int kb = kk * 64 + lq * 16;
        af[mf] = *(const bf16x8*)(sA + r * 128 + (kb ^ ((r & 7) << 4)));
      }
#pragma unroll
      for (int nf = 0; nf < 4; ++nf) {
        int r = wn * 64 + nf * 16 + l16;
        int kb = kk * 64 + lq * 16;
        bfr[nf] = *(const bf16x8*)(sB + r * 128 + (kb ^ ((r & 7) << 4)));
      }
#pragma unroll
      for (int mf = 0; mf < 4; ++mf)
#pragma unroll
        for (int nf = 0; nf < 4; ++nf)
          acc[mf][nf] = __builtin_amdgcn_mfma_f32_16x16x32_bf16(af[mf], bfr[nf], acc[mf][nf], 0, 0, 0);
    }
    __syncthreads();
  }

#pragma unroll
  for (int mf = 0; mf < 4; ++mf) {
#pragma unroll
    for (int nf = 0; nf < 4; ++nf) {
      const int row = row0 + wm * 64 + mf * 16 + lq * 4;
      const int col = col0 + wn * 64 + nf * 16 + l16;
      f32x4 v = acc[mf][nf];
      if constexpr (EPI == EPI_QK) {
        float qg = a0[col], qbt = a1[col], kg = a2[col], kbt = a3[col];
#pragma unroll
        for (int i = 0; i < 4; ++i) {
          float t = v[i];
          o0[(size_t)(row + i) * 128 + col] = f2b(t * qg + qbt);
          o1[(size_t)(row + i) * 128 + col] = f2b(t * kg + kbt);
        }
      } else if constexpr (EPI == EPI_OUT) {
        float bias = a0[col];
#pragma unroll
        for (int i = 0; i < 4; ++i)
          fout[(size_t)(row + i) * 512 + col] = v[i] + bias + xres[(size_t)(row + i) * 512 + col];
      }
    }
  }
}

// ---------- 256^2 16x16 minimal-barrier kernel (HID) — round-6 best ----------
__device__ __forceinline__ void stage_half(char* sbase, const char* gbase, long ld, int tid) {
#pragma unroll
  for (int i = 0; i < 2; ++i) {
    int o = (i * 512 + tid) * 16;
    int row = o >> 7;
    int cb = o & 127;
    int scb = cb ^ ((row & 7) << 4);
    const char* src = gbase + (long)row * ld + scb;
    __builtin_amdgcn_global_load_lds((const __attribute__((address_space(1))) void*)src,
                                     (__attribute__((address_space(3))) void*)(sbase + o),
                                     16, 0, 0);
  }
}

template <int EPI>
__global__ __launch_bounds__(512, 1) void gemm256(
    const char* Ab, const char* Bb, long sAbat, long sBbat,
    long lda, long ldb, int nkt, int nx,
    u16* o0, u16* o1,
    const float* a0, float* fout, const float* xres) {
  extern __shared__ __align__(16) char lds[];
  const int tid = threadIdx.x;
  const int lane = tid & 63;
  const int wave = tid >> 6;
  const int wm = wave >> 2;
  const int wn = wave & 3;
  const int l16 = lane & 15, lq = lane >> 4;
  const int bat = blockIdx.y;

  const int nwg = gridDim.x;
  const int qq = nwg >> 3;
  const int fid = blockIdx.x;
  const int swz = (fid & 7) * qq + (fid >> 3);
  const int row0 = (swz / nx) * 256;
  const int col0 = (swz % nx) * 256;

  const char* gA = Ab + (long)bat * sAbat + (long)row0 * lda;
  const char* gB = Bb + (long)bat * sBbat + (long)col0 * ldb;

  f32x4 acc[8][4];
#pragma unroll
  for (int i = 0; i < 8; ++i)
#pragma unroll
    for (int j = 0; j < 4; ++j) acc[i][j] = (f32x4){0.f, 0.f, 0.f, 0.f};

  const int kmask = (l16 & 7) << 4;
  const int kb0 = (lq * 16) ^ kmask;
  const int kb1 = (64 + lq * 16) ^ kmask;
  const int rB = (wn & 1) * 64;

  stage_half(lds + 32768, gB, ldb, tid);
  stage_half(lds + 32768 + 16384, gB + 128 * ldb, ldb, tid);
  stage_half(lds, gA, lda, tid);
  stage_half(lds + 16384, gA + 128 * lda, lda, tid);
  if (nkt > 1) {
    stage_half(lds + 65536 + 32768, gB + 128, ldb, tid);
    stage_half(lds + 65536 + 32768 + 16384, gB + 128 * ldb + 128, ldb, tid);
    VMCNT4();
  } else {
    VMCNT0();
  }
  BAR();

  bf16x8 af0[4], af1[4], afp0[4], afp1[4], bfr0[4], bfr1[4];
  {
    const char* myA = lds + wm * 16384;
    const char* myB = lds + 32768 + (wn >> 1) * 16384;
#pragma unroll
    for (int nf = 0; nf < 4; ++nf)
      bfr0[nf] = *(const bf16x8*)(myB + (rB + nf * 16 + l16) * 128 + kb0);
#pragma unroll
    for (int mf = 0; mf < 4; ++mf)
      af0[mf] = *(const bf16x8*)(myA + (mf * 16 + l16) * 128 + kb0);
  }

  for (int t = 0; t < nkt; ++t) {
    const char* bufc = lds + (t & 1) * 65536;
    const char* bufn = lds + ((t + 1) & 1) * 65536;
    const char* myA = bufc + wm * 16384;
    const char* myB = bufc + 32768 + (wn >> 1) * 16384;
    const char* nA = bufn + wm * 16384;
    const char* nB = bufn + 32768 + (wn >> 1) * 16384;
    char* stA = (char*)bufn;
    char* stB = (char*)bufc + 32768;
    const bool sA_ok = (t + 1) < nkt;
    const bool sB_ok = (t + 2) < nkt;

#pragma unroll
    for (int nf = 0; nf < 4; ++nf)
      bfr1[nf] = *(const bf16x8*)(myB + (rB + nf * 16 + l16) * 128 + kb1);
#pragma unroll
    for (int mf = 0; mf < 4; ++mf)
      af1[mf] = *(const bf16x8*)(myA + (mf * 16 + l16) * 128 + kb1);
    if (sA_ok) stage_half(stA, gA + (long)(t + 1) * 128, lda, tid);
    LGKM8();
    __builtin_amdgcn_s_setprio(1);
#pragma unroll
    for (int mf = 0; mf < 4; ++mf)
#pragma unroll
      for (int nf = 0; nf < 4; ++nf)
        acc[mf][nf] = __builtin_amdgcn_mfma_f32_16x16x32_bf16(af0[mf], bfr0[nf], acc[mf][nf], 0, 0, 0);
    __builtin_amdgcn_s_setprio(0);

#pragma unroll
    for (int mf = 0; mf < 4; ++mf)
      afp0[mf] = *(const bf16x8*)(myA + (64 + mf * 16 + l16) * 128 + kb0);
    if (sA_ok) stage_half(stA + 16384, gA + 128 * lda + (long)(t + 1) * 128, lda, tid);
    LGKM4();
    __builtin_amdgcn_s_setprio(1);
#pragma unroll
    for (int mf = 0; mf < 4; ++mf)
#pragma unroll
      for (int nf = 0; nf < 4; ++nf)
        acc[mf][nf] = __builtin_amdgcn_mfma_f32_16x16x32_bf16(af1[mf], bfr1[nf], acc[mf][nf], 0, 0, 0);
    __builtin_amdgcn_s_setprio(0);
    BAR();

#pragma unroll
    for (int mf = 0; mf < 4; ++mf)
      afp1[mf] = *(const bf16x8*)(myA + (64 + mf * 16 + l16) * 128 + kb1);
    if (sB_ok) stage_half(stB, gB + (long)(t + 2) * 128, ldb, tid);
    LGKM4();
    __builtin_amdgcn_s_setprio(1);
#pragma unroll
    for (int mf = 0; mf < 4; ++mf)
#pragma unroll
      for (int nf = 0; nf < 4; ++nf)
        acc[4 + mf][nf] = __builtin_amdgcn_mfma_f32_16x16x32_bf16(afp0[mf], bfr0[nf], acc[4 + mf][nf], 0, 0, 0);
    __builtin_amdgcn_s_setprio(0);
    if (sA_ok) {
      if (sB_ok) { VMCNT2(); } else { VMCNT0(); }
      BAR();
    }

    if (sA_ok) {
#pragma unroll
      for (int nf = 0; nf < 4; ++nf)
        bfr0[nf] = *(const bf16x8*)(nB + (rB + nf * 16 + l16) * 128 + kb0);
#pragma unroll
      for (int mf = 0; mf < 4; ++mf)
        af0[mf] = *(const bf16x8*)(nA + (mf * 16 + l16) * 128 + kb0);
    }
    if (sB_ok) stage_half(stB + 16384, gB + 128 * ldb + (long)(t + 2) * 128, ldb, tid);
    if (sA_ok) { LGKM8(); } else { LGKM0(); }
    __builtin_amdgcn_s_setprio(1);
#pragma unroll
    for (int mf = 0; mf < 4; ++mf)
#pragma unroll
      for (int nf = 0; nf < 4; ++nf)
        acc[4 + mf][nf] = __builtin_amdgcn_mfma_f32_16x16x32_bf16(afp1[mf], bfr1[nf], acc[4 + mf][nf], 0, 0, 0);
    __builtin_amdgcn_s_setprio(0);
    BAR();
  }

  // epilogue
#pragma unroll
  for (int mi = 0; mi < 8; ++mi) {
#pragma unroll
    for (int ni = 0; ni < 4; ++ni) {
      const int row = row0 + wm * 128 + mi * 16 + lq * 4;
      const int col = col0 + wn * 64 + ni * 16 + l16;
      f32x4 v = acc[mi][ni];
      if constexpr (EPI == EPI_HID) {
        float bias = a0[col];
        u16* dst = (col < 1024) ? (o0 + (size_t)col * 16384 + row)
                                : (o1 + (size_t)(col - 1024) * 16384 + row);
        *(ushort4*)dst = make_ushort4(f2b(v.x + bias), f2b(v.y + bias), f2b(v.z + bias), f2b(v.w + bias));
      }
    }
  }
}

// ---------- 1024-thread 256^2 PV kernel, 1 barrier/K-tile via A-dbuf + B-triple-ring ----------
// Round-16 best: 133 us, MfmaUtil 46%. Single frag set (a[4],b[4]) — the dual
// k-half prefetch variant (r17) exceeded the 128-VGPR/wave cap at 4 waves/SIMD
// and spilled to scratch (1.8 GB HBM writes, 6x slowdown). Do not re-add.
__device__ __forceinline__ void stage1k(char* s, const char* g, long ld, int tid) {
  int o = tid * 16;
  int row = o >> 7;
  int scb = (o & 127) ^ ((row & 7) << 4);
  __builtin_amdgcn_global_load_lds((const __attribute__((address_space(1))) void*)(g + (long)row * ld + scb),
                                   (__attribute__((address_space(3))) void*)(s + o), 16, 0, 0);
}

__global__ __launch_bounds__(1024, 1) void gemm1k_pv(
    const char* Ab, const char* Bb, long sAbat, long sBbat,
    long lda, long ldb, int nkt,
    u16* o0, const u16* g_t) {
  extern __shared__ __align__(16) char lds[];
  const int tid = threadIdx.x;
  const int lane = tid & 63;
  const int wave = tid >> 6;          // 0..15
  const int wm = wave >> 2;           // 0..3 -> rows wm*64
  const int wn = wave & 3;            // 0..3 -> cols wn*64
  const int l16 = lane & 15, lq = lane >> 4;
  const int bat = blockIdx.y;

  const int fid = blockIdx.x;         // 64 per batch
  const int r = fid & 15;             // row-tile
  const int c = fid >> 4;             // col-tile
  const int row0 = r * 256;
  const int col0 = c * 256;

  const char* gA = Ab + (long)bat * sAbat + (long)row0 * lda;
  const char* gB = Bb + (long)bat * sBbat + (long)col0 * ldb;

  f32x4 acc[4][4];
#pragma unroll
  for (int i = 0; i < 4; ++i)
#pragma unroll
    for (int j = 0; j < 4; ++j) acc[i][j] = (f32x4){0.f, 0.f, 0.f, 0.f};

  const int kmask = (l16 & 7) << 4;
  const int kb0 = (lq * 16) ^ kmask;
  const int kb1 = (64 + lq * 16) ^ kmask;
  const int rA = (wm & 1) * 64;
  const int rB = (wn & 1) * 64;

  // prologue: B(0) @slot0, A(0) @buf0, B(1) @slot1; VMCNT2 leaves B(1) pending.
  stage1k(lds + 65536, gB, ldb, tid);
  stage1k(lds + 65536 + 16384, gB + 128 * ldb, ldb, tid);
  stage1k(lds, gA, lda, tid);
  stage1k(lds + 16384, gA + 128 * lda, lda, tid);
  if (nkt > 1) {
    stage1k(lds + 98304, gB + 128, ldb, tid);
    stage1k(lds + 98304 + 16384, gB + 128 * ldb + 128, ldb, tid);
    VMCNT2();
  } else {
    VMCNT0();
  }
  BAR();

  bf16x8 a[4], b[4];
  {
    const char* myA = lds + (wm >> 1) * 16384;
    const char* myB = lds + 65536 + (wn >> 1) * 16384;
#pragma unroll
    for (int mi = 0; mi < 4; ++mi)
      a[mi] = *(const bf16x8*)(myA + (rA + mi * 16 + l16) * 128 + kb0);
#pragma unroll
    for (int ni = 0; ni < 4; ++ni)
      b[ni] = *(const bf16x8*)(myB + (rB + ni * 16 + l16) * 128 + kb0);
  }

  int bs_c = 0;  // B ring slot of tile t (0..2)
  for (int t = 0; t < nkt; ++t) {
    const char* myA = lds + (t & 1) * 32768 + (wm >> 1) * 16384;
    const char* myB = lds + 65536 + bs_c * 32768 + (wn >> 1) * 16384;
    const bool sA = (t + 1) < nkt;
    const bool sB = (t + 2) < nkt;
    const int bs_n = (bs_c + 1 == 3) ? 0 : bs_c + 1;  // slot of t+1
    const int bs_s = (bs_n + 1 == 3) ? 0 : bs_n + 1;  // slot of t+2 (stage target)

    // ---- P1: MFMA kh0; issue kh1 reads; stage A(t+1)
    LGKM0();
    __builtin_amdgcn_s_setprio(1);
#pragma unroll
    for (int mi = 0; mi < 4; ++mi)
#pragma unroll
      for (int ni = 0; ni < 4; ++ni)
        acc[mi][ni] = __builtin_amdgcn_mfma_f32_16x16x32_bf16(a[mi], b[ni], acc[mi][ni], 0, 0, 0);
    __builtin_amdgcn_s_setprio(0);
#pragma unroll
    for (int mi = 0; mi < 4; ++mi)
      a[mi] = *(const bf16x8*)(myA + (rA + mi * 16 + l16) * 128 + kb1);
#pragma unroll
    for (int ni = 0; ni < 4; ++ni)
      b[ni] = *(const bf16x8*)(myB + (rB + ni * 16 + l16) * 128 + kb1);
    if (sA) {
      char* stA = lds + ((t + 1) & 1) * 32768;
      stage1k(stA, gA + (long)(t + 1) * 128, lda, tid);
      stage1k(stA + 16384, gA + 128 * lda + (long)(t + 1) * 128, lda, tid);
    }

    // ---- P2: MFMA kh1; stage B(t+2); VMCNT2+BAR; pre-read next kh0
    LGKM0();
    __builtin_amdgcn_s_setprio(1);
#pragma unroll
    for (int mi = 0; mi < 4; ++mi)
#pragma unroll
      for (int ni = 0; ni < 4; ++ni)
        acc[mi][ni] = __builtin_amdgcn_mfma_f32_16x16x32_bf16(a[mi], b[ni], acc[mi][ni], 0, 0, 0);
    __builtin_amdgcn_s_setprio(0);
    if (sB) {
      char* stB = lds + 65536 + bs_s * 32768;
      stage1k(stB, gB + (long)(t + 2) * 128, ldb, tid);
      stage1k(stB + 16384, gB + 128 * ldb + (long)(t + 2) * 128, ldb, tid);
    }
    if (sA) {
      if (sB) { VMCNT2(); } else { VMCNT0(); }
      BAR();  // A(t+1), B(t+1) landed and visible
      const char* nA = lds + ((t + 1) & 1) * 32768 + (wm >> 1) * 16384;
      const char* nB = lds + 65536 + bs_n * 32768 + (wn >> 1) * 16384;
#pragma unroll
      for (int mi = 0; mi < 4; ++mi)
        a[mi] = *(const bf16x8*)(nA + (rA + mi * 16 + l16) * 128 + kb0);
#pragma unroll
      for (int ni = 0; ni < 4; ++ni)
        b[ni] = *(const bf16x8*)(nB + (rB + ni * 16 + l16) * 128 + kb0);
    }
    bs_c = bs_n;
  }

  // epilogue: * gate, store bf16 out1
#pragma unroll
  for (int mi = 0; mi < 4; ++mi) {
#pragma unroll
    for (int ni = 0; ni < 4; ++ni) {
      const int row = row0 + wm * 64 + mi * 16 + lq * 4;
      const int col = col0 + wn * 64 + ni * 16 + l16;
      f32x4 v = acc[mi][ni];
      const u16* gp = g_t + (size_t)col * 16384 + (size_t)bat * 4096 + row;
      ushort4 g = *(const ushort4*)gp;
      u16* dst = o0 + (size_t)bat * 4096 * 1024;
      dst[(size_t)(row + 0) * 1024 + col] = f2b(v.x * b2f(g.x));
      dst[(size_t)(row + 1) * 1024 + col] = f2b(v.y * b2f(g.y));
      dst[(size_t)(row + 2) * 1024 + col] = f2b(v.z * b2f(g.z));
      dst[(size_t)(row + 3) * 1024 + col] = f2b(v.w * b2f(g.w));
    }
  }
}

// ---------- lean single-stage ATTN (K=128 staged once), software-pipelined ----------
__device__ __forceinline__ void stage256(char* s, const char* g, int tid) {
#pragma unroll
  for (int i = 0; i < 8; ++i) {
    int o = (i * 512 + tid) * 16;
    int row = o >> 8;
    int cb = o & 255;
    int scb = cb ^ ((row & 7) << 4);
    __builtin_amdgcn_global_load_lds((const __attribute__((address_space(1))) void*)(g + (long)row * 256 + scb),
                                     (__attribute__((address_space(3))) void*)(s + o), 16, 0, 0);
  }
}

__global__ __launch_bounds__(512, 1) void attn_lean(
    const char* Kb, const char* Qb, u16* o0, int nx) {
  extern __shared__ __align__(16) char lds[];
  const int tid = threadIdx.x;
  const int lane = tid & 63;
  const int wave = tid >> 6;
  const int wm = wave >> 2;        // j half
  const int wn = wave & 3;         // q quarter
  const int l16 = lane & 15, lq = lane >> 4;
  const int bat = blockIdx.y;

  const int nwg = gridDim.x;       // 256 (%8==0)
  const int qq = nwg >> 3;
  const int fid = blockIdx.x;
  const int swz = (fid & 7) * qq + (fid >> 3);
  const int row0 = (swz / nx) * 256;   // j
  const int col0 = (swz % nx) * 256;   // q

  const char* gA = Kb + (size_t)bat * 4096 * 256 + (size_t)row0 * 256;
  const char* gB = Qb + (size_t)bat * 4096 * 256 + (size_t)col0 * 256;

  stage256(lds, gA, tid);
  stage256(lds + 65536, gB, tid);
  VMCNT0();
  BAR();

  const char* myA = lds + wm * 32768;                 // 128 j-rows x 256B
  const char* myB = lds + 65536 + (wn >> 1) * 32768;  // 128 q-rows x 256B
  const int rB = (wn & 1) * 64;
  const int kmask = (l16 & 7) << 4;

  f32x4 acc[8][4];
#pragma unroll
  for (int i = 0; i < 8; ++i)
#pragma unroll
    for (int j = 0; j < 4; ++j) acc[i][j] = (f32x4){0.f, 0.f, 0.f, 0.f};

  bf16x8 aC[8], bC[4], aN[8], bN[4];

#define LOADK(A, B, kk)                                                        \
  do {                                                                         \
    const int kb_ = ((kk) * 64 + lq * 16) ^ kmask;                             \
    _Pragma("unroll") for (int mf = 0; mf < 8; ++mf)                           \
        A[mf] = *(const bf16x8*)(myA + (mf * 16 + l16) * 256 + kb_);           \
    _Pragma("unroll") for (int nf = 0; nf < 4; ++nf)                           \
        B[nf] = *(const bf16x8*)(myB + (rB + nf * 16 + l16) * 256 + kb_);      \
  } while (0)
#define MMK(A, B)                                                              \
  do {                                                                         \
    _Pragma("unroll") for (int mf = 0; mf < 8; ++mf)                           \
        _Pragma("unroll") for (int nf = 0; nf < 4; ++nf)                       \
            acc[mf][nf] =                                                      \
        __builtin_amdgcn_mfma_f32_16x16x32_bf16(A[mf], B[nf], acc[mf][nf], 0, 0, 0); \
  } while (0)

  LOADK(aC, bC, 0);
  LOADK(aN, bN, 1);
  MMK(aC, bC);
  LOADK(aC, bC, 2);
  MMK(aN, bN);
  LOADK(aN, bN, 3);
  MMK(aC, bC);
  MMK(aN, bN);
#undef LOADK
#undef MMK

  const float scale = 0.088388347648318447f;  // 128^-0.5
  u16* dst = o0 + (size_t)bat * 4096 * 4096;
#pragma unroll
  for (int mi = 0; mi < 8; ++mi) {
#pragma unroll
    for (int ni = 0; ni < 4; ++ni) {
      const int row = row0 + wm * 128 + mi * 16 + lq * 4;   // j (4 consecutive)
      const int col = col0 + wn * 64 + ni * 16 + l16;       // q
      f32x4 v = acc[mi][ni];
      float t0 = v.x * scale; t0 = t0 > 0.f ? t0 * t0 : 0.f;
      float t1 = v.y * scale; t1 = t1 > 0.f ? t1 * t1 : 0.f;
      float t2 = v.z * scale; t2 = t2 > 0.f ? t2 * t2 : 0.f;
      float t3 = v.w * scale; t3 = t3 > 0.f ? t3 * t3 : 0.f;
      *(ushort4*)(dst + (size_t)col * 4096 + row) =
          make_ushort4(f2b(t0), f2b(t1), f2b(t2), f2b(t3));
    }
  }
}

__global__ void conv_b(const float* in, u16* out, int n) {
  int i = (blockIdx.x * blockDim.x + threadIdx.x) * 4;
  if (i >= n) return;
  float4 f = *(const float4*)(in + i);
  *(ushort4*)(out + i) = make_ushort4(f2b(f.x), f2b(f.y), f2b(f.z), f2b(f.w));
}

// out[c][r] = bf16(in[r][c]) via LDS 32x32 tile (+1 pad) — both sides coalesced
__global__ void transpose_lds(const float* in, u16* out, int R, int C) {
  __shared__ float t[32][33];
  const int tx = threadIdx.x & 31, ty = threadIdx.x >> 5;  // 32x8
  const int c0 = blockIdx.x * 32, r0 = blockIdx.y * 32;
#pragma unroll
  for (int i = 0; i < 32; i += 8)
    t[ty + i][tx] = in[(size_t)(r0 + ty + i) * C + c0 + tx];
  __syncthreads();
#pragma unroll
  for (int i = 0; i < 32; i += 8)
    out[(size_t)(c0 + ty + i) * R + r0 + tx] = f2b(t[tx][ty + i]);
}

extern "C" void kernel_launch(void* const* d_in, const int* in_sizes, int n_in,
                              void* d_out, int out_size, void* d_ws, size_t ws_size,
                              hipStream_t stream) {
  const float* x = (const float*)d_in[0];
  const float* w_hidden = (const float*)d_in[1];
  const float* b_hidden = (const float*)d_in[2];
  const float* w_qk = (const float*)d_in[3];
  const float* q_gamma = (const float*)d_in[4];
  const float* q_beta = (const float*)d_in[5];
  const float* k_gamma = (const float*)d_in[6];
  const float* k_beta = (const float*)d_in[7];
  const float* w_out = (const float*)d_in[8];
  const float* b_out = (const float*)d_in[9];
  float* out = (float*)d_out;

  char* ws = (char*)d_ws;
  size_t off = 0;
  auto alloc = [&](size_t bytes) { char* p = ws + off; off += (bytes + 255) & ~255ull; return p; };
  u16* xb     = (u16*)alloc(16384ull * 512 * 2);
  u16* wh_t   = (u16*)alloc(2048ull * 512 * 2);
  u16* wqk_t  = (u16*)alloc(128ull * 512 * 2);
  u16* wout_t = (u16*)alloc(512ull * 1024 * 2);
  u16* v_t    = (u16*)alloc(1024ull * 16384 * 2);
  u16* g_t    = (u16*)alloc(1024ull * 16384 * 2);
  u16* qb_a   = (u16*)alloc(16384ull * 128 * 2);
  u16* kb_a   = (u16*)alloc(16384ull * 128 * 2);
  u16* attnb  = (u16*)alloc(4ull * 4096 * 4096 * 2);
  u16* out1b  = (u16*)alloc(16384ull * 1024 * 2);

  (void)hipFuncSetAttribute((const void*)gemm256<EPI_HID>, hipFuncAttributeMaxDynamicSharedMemorySize, 131072);
  (void)hipFuncSetAttribute((const void*)gemm1k_pv, hipFuncAttributeMaxDynamicSharedMemorySize, 163840);
  (void)hipFuncSetAttribute((const void*)attn_lean, hipFuncAttributeMaxDynamicSharedMemorySize, 131072);

  conv_b<<<(16384 * 512 / 4 + 255) / 256, 256, 0, stream>>>(x, xb, 16384 * 512);
  transpose_lds<<<dim3(2048 / 32, 512 / 32), 256, 0, stream>>>(w_hidden, wh_t, 512, 2048);
  transpose_lds<<<dim3(128 / 32, 512 / 32), 256, 0, stream>>>(w_qk, wqk_t, 512, 128);
  transpose_lds<<<dim3(512 / 32, 1024 / 32), 256, 0, stream>>>(w_out, wout_t, 1024, 512);

  // GEMM1: hid = x @ Wh (+bias) -> v_t, g_t (transposed bf16). M=16384 N=2048 K=512
  gemm256<EPI_HID><<<dim3(512, 1), 512, 131072, stream>>>(
      (const char*)xb, (const char*)wh_t, 0, 0, 1024, 1024, 8, 8,
      v_t, g_t, b_hidden, nullptr, nullptr);
  // GEMM2: qk = x @ Wqk -> q,k (offset-scale). N=128
  gemm_tn<EPI_QK><<<dim3(1, 128, 1), 256, 0, stream>>>(
      (const char*)xb, (const char*)wqk_t, 0, 0, 1024, 1024, 8,
      qb_a, kb_a, q_gamma, q_beta, k_gamma, k_beta, nullptr, nullptr);
  // sim: C[j][q] = K @ Q^T, relu^2(scale*) -> attn[q][j] bf16 (lean single-stage)
  attn_lean<<<dim3(256, 4), 512, 131072, stream>>>(
      (const char*)kb_a, (const char*)qb_a, attnb, 16);
  // out1 = (attn @ v) * gate. per batch M=4096 N=1024 K=4096 — 1-barrier ring kernel
  gemm1k_pv<<<dim3(64, 4), 1024, 163840, stream>>>(
      (const char*)attnb, (const char*)v_t, 4096ll * 8192, 8192, 8192, 32768, 64,
      out1b, g_t);
  // out = out1 @ Wout + b_out + x. M=16384 N=512 K=1024
  gemm_tn<EPI_OUT><<<dim3(4, 128, 1), 256, 0, stream>>>(
      (const char*)out1b, (const char*)wout_t, 0, 0, 2048, 2048, 16,
      nullptr, nullptr, b_out, nullptr, nullptr, nullptr, out, x);
}